// Round 2
// baseline (345.750 us; speedup 1.0000x reference)
//
#include <hip/hip_runtime.h>
#include <hip/hip_bf16.h>

#define SCALE 0.125f

typedef __attribute__((ext_vector_type(8))) __bf16 bf16x8;
typedef __attribute__((ext_vector_type(4))) float f32x4;
typedef __attribute__((ext_vector_type(4))) short s16x4;
typedef __hip_bfloat16 bf16;

__device__ __forceinline__ void gl_lds16(const bf16* g, bf16* l) {
  __builtin_amdgcn_global_load_lds(
      (const __attribute__((address_space(1))) void*)g,
      (__attribute__((address_space(3))) void*)l, 16, 0, 0);
}

__device__ __forceinline__ f32x4 zf4() {
  f32x4 v; v[0] = 0.f; v[1] = 0.f; v[2] = 0.f; v[3] = 0.f; return v;
}

// ---------------- fp32 -> bf16 copy (4 elems/thread) ----------------
__global__ __launch_bounds__(256) void conv_bf16_k(const float* __restrict__ in,
                                                   bf16* __restrict__ out, int n4) {
  int i = blockIdx.x * 256 + threadIdx.x;
  if (i >= n4) return;
  const float4 v = reinterpret_cast<const float4*>(in)[i];
  union { bf16 h4[4]; s16x4 s; } u;
  u.h4[0] = __float2bfloat16(v.x);
  u.h4[1] = __float2bfloat16(v.y);
  u.h4[2] = __float2bfloat16(v.z);
  u.h4[3] = __float2bfloat16(v.w);
  reinterpret_cast<s16x4*>(out)[i] = u.s;
}

// ---------------- fp32 [K][N] -> bf16 [N][K] transpose ----------------
__global__ __launch_bounds__(256) void transp_k(const float* __restrict__ W,
                                                bf16* __restrict__ Wt, int K, int N) {
  __shared__ float t[32][33];
  const int tx = threadIdx.x, ty = threadIdx.y;
  const int n0 = blockIdx.x * 32, k0 = blockIdx.y * 32;
#pragma unroll
  for (int i = 0; i < 4; ++i)
    t[ty + 8 * i][tx] = W[(k0 + ty + 8 * i) * N + n0 + tx];
  __syncthreads();
#pragma unroll
  for (int i = 0; i < 4; ++i)
    Wt[(n0 + ty + 8 * i) * K + k0 + tx] = __float2bfloat16(t[tx][ty + 8 * i]);
}

// ---------------- bf16 GEMM, 128x128 tile, BK=32, m97 structure ----------------
struct GemmP {
  const bf16* A;    // [M][1024] row-major
  const bf16* B0;   // Bt [N][1024]
  const bf16* B1;   // gate weights (EPI1) Bt
  const bf16* sT;   // EPI1: s in [B,H,N,D]
  bf16 *q, *k, *vt, *gate, *obf;
  float* out;
  const float* bias;
};

template <int EPI>
__global__ __launch_bounds__(256) void gemm_k(GemmP p) {
  constexpr int K = 1024;
  __shared__ bf16 As[128 * 32];
  __shared__ bf16 Bs[128 * 32];
  const int tid = threadIdx.x;
  const int wid = tid >> 6, lane = tid & 63;
  const int l15 = lane & 15, l4 = lane >> 4;
  const int wr = wid >> 1, wc = wid & 1;
  const int m0 = blockIdx.y * 128, n0 = blockIdx.x * 128;
  const bf16* Arow = p.A + m0 * K;
  const bf16* Brow;
  if (EPI == 1 && n0 >= 3072) Brow = p.B1 + (n0 - 3072) * K;
  else Brow = p.B0 + n0 * K;

  f32x4 acc[4][4];
#pragma unroll
  for (int m = 0; m < 4; ++m)
#pragma unroll
    for (int n = 0; n < 4; ++n) acc[m][n] = zf4();

  const int srow = tid >> 2, skc = tid & 3;
  for (int kt = 0; kt < K; kt += 32) {
#pragma unroll
    for (int it = 0; it < 2; ++it) {
      gl_lds16(Arow + (it * 64 + srow) * K + kt + skc * 8, As + it * 2048 + wid * 512);
      gl_lds16(Brow + (it * 64 + srow) * K + kt + skc * 8, Bs + it * 2048 + wid * 512);
    }
    __syncthreads();
    bf16x8 af[4], bfr[4];
#pragma unroll
    for (int m = 0; m < 4; ++m)
      af[m] = *reinterpret_cast<const bf16x8*>(&As[(wr * 64 + m * 16 + l15) * 32 + 8 * l4]);
#pragma unroll
    for (int n = 0; n < 4; ++n)
      bfr[n] = *reinterpret_cast<const bf16x8*>(&Bs[(wc * 64 + n * 16 + l15) * 32 + 8 * l4]);
#pragma unroll
    for (int m = 0; m < 4; ++m)
#pragma unroll
      for (int n = 0; n < 4; ++n)
        acc[m][n] = __builtin_amdgcn_mfma_f32_16x16x32_bf16(af[m], bfr[n], acc[m][n], 0, 0, 0);
    __syncthreads();
  }

  // epilogue
#pragma unroll
  for (int m = 0; m < 4; ++m) {
    const int gr0 = m0 + wr * 64 + m * 16 + l4 * 4;
    const int bb = gr0 >> 11;
    const int nn0 = gr0 & 2047;
#pragma unroll
    for (int n = 0; n < 4; ++n) {
      const int gc = n0 + wc * 64 + n * 16 + l15;
      if (EPI == 0) {
        const int h = gc >> 6, d = gc & 63;
        bf16* dst = p.obf + ((bb * 16 + h) * 2048 + nn0) * 64 + d;
#pragma unroll
        for (int r = 0; r < 4; ++r) dst[r * 64] = __float2bfloat16(acc[m][n][r]);
      } else if (EPI == 1) {
        if (gc < 3072) {
          const int t = gc >> 10, hd = gc & 1023;
          const int h = hd >> 6, d = hd & 63;
          const int base = ((bb * 16 + h) * 2048 + nn0) * 64 + d;
          if (t == 0) {
#pragma unroll
            for (int r = 0; r < 4; ++r) p.q[base + r * 64] = __float2bfloat16(acc[m][n][r]);
          } else if (t == 1) {
#pragma unroll
            for (int r = 0; r < 4; ++r)
              p.k[base + r * 64] =
                  __float2bfloat16(acc[m][n][r] + __bfloat162float(p.sT[base + r * 64]));
          } else {
            union { bf16 h4[4]; s16x4 s; } u;
#pragma unroll
            for (int r = 0; r < 4; ++r) u.h4[r] = __float2bfloat16(acc[m][n][r]);
            *reinterpret_cast<s16x4*>(&p.vt[((bb * 16 + h) * 64 + d) * 2048 + nn0]) = u.s;
          }
        } else {
          const int gcc = gc - 3072;
#pragma unroll
          for (int r = 0; r < 4; ++r)
            p.gate[(gr0 + r) * 1024 + gcc] = __float2bfloat16(acc[m][n][r]);
        }
      } else {
        const float bias = p.bias[gc];
#pragma unroll
        for (int r = 0; r < 4; ++r) p.out[(gr0 + r) * 1024 + gc] = acc[m][n][r] + bias;
      }
    }
  }
}

// ---------------- flash attention ----------------
// qT,kTb: [BH][N][D] bf16 (k already has s added). vTt: [BH][D][N] bf16.
// gateb: [B*N][C] bf16. attng: [B*N][C] bf16 (gated attention output).
__global__ __launch_bounds__(256) void flash_k(const bf16* __restrict__ qT,
                                               const bf16* __restrict__ kTb,
                                               const bf16* __restrict__ vTt,
                                               const bf16* __restrict__ gateb,
                                               bf16* __restrict__ attng) {
  __shared__ bf16 Ks[64 * 64];       // [key][d], XOR-swizzled 16B chunks
  __shared__ bf16 Vs[64 * 64];       // [d][key], XOR-swizzled 16B chunks
  __shared__ bf16 Ps[4][16 * 72];    // per-wave P, padded stride 72
  const int tid = threadIdx.x;
  const int wid = tid >> 6, lane = tid & 63;
  const int l15 = lane & 15, l4 = lane >> 4;
  const int qt = blockIdx.x, bh = blockIdx.y;
  const int qr0 = qt * 64 + wid * 16;
  const bf16* qbase = qT + (bh * 2048 + qr0) * 64;
  const bf16x8 qf0 = *reinterpret_cast<const bf16x8*>(&qbase[l15 * 64 + 8 * l4]);
  const bf16x8 qf1 = *reinterpret_cast<const bf16x8*>(&qbase[l15 * 64 + 32 + 8 * l4]);
  const bf16* kbase = kTb + bh * 2048 * 64;
  const bf16* vbase = vTt + bh * 64 * 2048;
  f32x4 o[4];
  float mrun[4], lrun[4];
#pragma unroll
  for (int i = 0; i < 4; ++i) { o[i] = zf4(); mrun[i] = -1e30f; lrun[i] = 0.f; }
  const int srow = tid >> 3, sc = tid & 7;

  for (int kt = 0; kt < 32; ++kt) {
#pragma unroll
    for (int it = 0; it < 2; ++it) {
      const int row = it * 32 + srow;
      const int c2 = sc ^ (row & 7);  // pre-swizzled global source; LDS stays linear
      gl_lds16(kbase + (kt * 64 + row) * 64 + c2 * 8, Ks + it * 2048 + wid * 512);
      gl_lds16(vbase + row * 2048 + kt * 64 + c2 * 8, Vs + it * 2048 + wid * 512);
    }
    __syncthreads();

    // S = Q K^T  (per wave: 16 q-rows x 64 keys)
    f32x4 sa[4];
#pragma unroll
    for (int n = 0; n < 4; ++n) sa[n] = zf4();
#pragma unroll
    for (int kk = 0; kk < 2; ++kk) {
      const bf16x8 qv = kk ? qf1 : qf0;
#pragma unroll
      for (int n = 0; n < 4; ++n) {
        const int key = n * 16 + l15;
        const bf16x8 kv = *reinterpret_cast<const bf16x8*>(
            &Ks[key * 64 + ((kk * 4 + l4) ^ (key & 7)) * 8]);
        sa[n] = __builtin_amdgcn_mfma_f32_16x16x32_bf16(qv, kv, sa[n], 0, 0, 0);
      }
    }

    // online softmax (rows (l4*4+r); reduce across 16 lanes of same l4-group)
    float mt[4];
#pragma unroll
    for (int r = 0; r < 4; ++r)
      mt[r] = fmaxf(fmaxf(sa[0][r], sa[1][r]), fmaxf(sa[2][r], sa[3][r])) * SCALE;
#pragma unroll
    for (int off = 1; off <= 8; off <<= 1) {
#pragma unroll
      for (int r = 0; r < 4; ++r) mt[r] = fmaxf(mt[r], __shfl_xor(mt[r], off, 64));
    }
    float fac[4], psum[4];
#pragma unroll
    for (int r = 0; r < 4; ++r) {
      const float mn = fmaxf(mrun[r], mt[r]);
      fac[r] = __expf(mrun[r] - mn);
      mrun[r] = mn;
      psum[r] = 0.f;
    }
#pragma unroll
    for (int n = 0; n < 4; ++n) {
#pragma unroll
      for (int r = 0; r < 4; ++r) {
        const float pv = __expf(sa[n][r] * SCALE - mrun[r]);
        psum[r] += pv;
        Ps[wid][(l4 * 4 + r) * 72 + n * 16 + l15] = __float2bfloat16(pv);
      }
    }
#pragma unroll
    for (int off = 1; off <= 8; off <<= 1) {
#pragma unroll
      for (int r = 0; r < 4; ++r) psum[r] += __shfl_xor(psum[r], off, 64);
    }
#pragma unroll
    for (int r = 0; r < 4; ++r) lrun[r] = lrun[r] * fac[r] + psum[r];
#pragma unroll
    for (int nd = 0; nd < 4; ++nd)
#pragma unroll
      for (int r = 0; r < 4; ++r) o[nd][r] *= fac[r];
    __syncthreads();  // P visible

    // O += P V
#pragma unroll
    for (int kk = 0; kk < 2; ++kk) {
      const bf16x8 pa = *reinterpret_cast<const bf16x8*>(&Ps[wid][l15 * 72 + kk * 32 + 8 * l4]);
#pragma unroll
      for (int nd = 0; nd < 4; ++nd) {
        const int d = nd * 16 + l15;
        const bf16x8 vv = *reinterpret_cast<const bf16x8*>(
            &Vs[d * 64 + ((kk * 4 + l4) ^ (d & 7)) * 8]);
        o[nd] = __builtin_amdgcn_mfma_f32_16x16x32_bf16(pa, vv, o[nd], 0, 0, 0);
      }
    }
    __syncthreads();  // before restaging Ks/Vs
  }

  const int bb = bh >> 4, h = bh & 15;
  float inv[4];
#pragma unroll
  for (int r = 0; r < 4; ++r) inv[r] = 1.0f / lrun[r];
#pragma unroll
  for (int nd = 0; nd < 4; ++nd) {
    const int col = h * 64 + nd * 16 + l15;
#pragma unroll
    for (int r = 0; r < 4; ++r) {
      const int grow = bb * 2048 + qr0 + l4 * 4 + r;
      const int gi = grow * 1024 + col;
      const float val = o[nd][r] * inv[r] * __bfloat162float(gateb[gi]);
      attng[gi] = __float2bfloat16(val);
    }
  }
}

// ---------------- launcher ----------------
extern "C" void kernel_launch(void* const* d_in, const int* in_sizes, int n_in,
                              void* d_out, int out_size, void* d_ws, size_t ws_size,
                              hipStream_t stream) {
  const float* x = (const float*)d_in[0];
  const float* e = (const float*)d_in[1];
  const float* Wqkv = (const float*)d_in[2];
  const float* Ws = (const float*)d_in[3];
  const float* Wgate = (const float*)d_in[4];
  const float* Wproj = (const float*)d_in[5];
  const float* bproj = (const float*)d_in[6];
  float* out = (float*)d_out;

  char* w = (char*)d_ws;
  auto carve = [&](size_t bytes) -> void* {
    void* p = (void*)w;
    w += (bytes + 255) & ~size_t(255);
    return p;
  };
  // time-disjoint aliases: qT overlays ebf (ebf dead after gemm<0>);
  // attng overlays sT (sT dead after gemm<1>).
  bf16* xbf    = (bf16*)carve(4096UL * 1024 * 2);
  bf16* ebf    = (bf16*)carve(4096UL * 1024 * 2);
  bf16* Wqkvt  = (bf16*)carve(3072UL * 1024 * 2);
  bf16* Wst    = (bf16*)carve(1024UL * 1024 * 2);
  bf16* Wgatet = (bf16*)carve(1024UL * 1024 * 2);
  bf16* Wprojt = (bf16*)carve(1024UL * 1024 * 2);
  bf16* kTb    = (bf16*)carve(32UL * 2048 * 64 * 2);
  bf16* vTt    = (bf16*)carve(32UL * 64 * 2048 * 2);
  bf16* sT     = (bf16*)carve(32UL * 2048 * 64 * 2);
  bf16* gateb  = (bf16*)carve(4096UL * 1024 * 2);
  bf16* qT     = ebf;
  bf16* attng  = sT;

  conv_bf16_k<<<4096, 256, 0, stream>>>(x, xbf, 1048576);
  conv_bf16_k<<<4096, 256, 0, stream>>>(e, ebf, 1048576);
  transp_k<<<dim3(96, 32), dim3(32, 8), 0, stream>>>(Wqkv, Wqkvt, 1024, 3072);
  transp_k<<<dim3(32, 32), dim3(32, 8), 0, stream>>>(Ws, Wst, 1024, 1024);
  transp_k<<<dim3(32, 32), dim3(32, 8), 0, stream>>>(Wgate, Wgatet, 1024, 1024);
  transp_k<<<dim3(32, 32), dim3(32, 8), 0, stream>>>(Wproj, Wprojt, 1024, 1024);

  GemmP ps{};
  ps.A = ebf; ps.B0 = Wst; ps.obf = sT;
  gemm_k<0><<<dim3(8, 32), 256, 0, stream>>>(ps);

  GemmP pq{};
  pq.A = xbf; pq.B0 = Wqkvt; pq.B1 = Wgatet; pq.sT = sT;
  pq.q = qT; pq.k = kTb; pq.vt = vTt; pq.gate = gateb;
  gemm_k<1><<<dim3(32, 32), 256, 0, stream>>>(pq);

  flash_k<<<dim3(32, 32), 256, 0, stream>>>(qT, kTb, vTt, gateb, attng);

  GemmP pp{};
  pp.A = attng; pp.B0 = Wprojt; pp.out = out; pp.bias = bproj;
  gemm_k<2><<<dim3(8, 32), 256, 0, stream>>>(pp);
}